// Round 1
// baseline (2734.644 us; speedup 1.0000x reference)
//
#include <hip/hip_runtime.h>
#include <hip/hip_bf16.h>
#include <math.h>

// Problem constants (derived from in_sizes at launch where possible)
#define DD 256
#define HH 128
#define OO 64

// ---------------------------------------------------------------------------
// degree kernels
// ---------------------------------------------------------------------------
__global__ void init_deg_kernel(float* __restrict__ deg_g, float* __restrict__ deg_p, int n) {
    int i = blockIdx.x * blockDim.x + threadIdx.x;
    if (i < n) { deg_g[i] = 1.0f; deg_p[i] = 1.0f; }  // self-loop weight
}

__global__ void accum_deg_kernel(const int* __restrict__ row, const float* __restrict__ ppmi,
                                 float* __restrict__ deg_g, float* __restrict__ deg_p, int e) {
    int i = blockIdx.x * blockDim.x + threadIdx.x;
    if (i < e) {
        int r = row[i];
        atomicAdd(&deg_g[r], 1.0f);
        atomicAdd(&deg_p[r], ppmi[i]);
    }
}

__global__ void deg_to_dis_kernel(float* __restrict__ deg_g, float* __restrict__ deg_p, int n) {
    int i = blockIdx.x * blockDim.x + threadIdx.x;
    if (i < n) {
        deg_g[i] = 1.0f / sqrtf(deg_g[i]);   // deg >= 1 always (self loop)
        deg_p[i] = 1.0f / sqrtf(deg_p[i]);
    }
}

// ---------------------------------------------------------------------------
// Tiled SGEMM: C[M,Ncols] = A[M,K] @ B[K,Ncols], row-major.
// One block covers BM rows x BN cols; requires BN == Ncols (grid is 1-D over rows).
// ---------------------------------------------------------------------------
template<int BM, int BN, int BK, int TM, int TN>
__launch_bounds__((BM / TM) * (BN / TN))
__global__ void sgemm_kernel(const float* __restrict__ A, const float* __restrict__ B,
                             float* __restrict__ C, int M, int K, int Ncols) {
    constexpr int THREADS = (BM / TM) * (BN / TN);
    __shared__ float As[BK][BM + 1];   // transposed A tile (pad to dodge bank conflicts)
    __shared__ float Bs[BK][BN];

    const int tid  = threadIdx.x;
    const int row0 = blockIdx.x * BM;
    const int tcol = tid % (BN / TN);
    const int trow = tid / (BN / TN);

    float acc[TM][TN];
#pragma unroll
    for (int i = 0; i < TM; ++i)
#pragma unroll
        for (int j = 0; j < TN; ++j) acc[i][j] = 0.0f;

    for (int k0 = 0; k0 < K; k0 += BK) {
        constexpr int A_ITERS = (BM * BK) / THREADS;
#pragma unroll
        for (int l = 0; l < A_ITERS; ++l) {
            int lin = tid + l * THREADS;
            int bm = lin / BK, kk = lin % BK;
            int gr = row0 + bm;
            As[kk][bm] = (gr < M) ? A[(size_t)gr * K + k0 + kk] : 0.0f;
        }
        constexpr int B_ITERS = (BK * BN) / THREADS;
#pragma unroll
        for (int l = 0; l < B_ITERS; ++l) {
            int lin = tid + l * THREADS;
            int kk = lin / BN, bn = lin % BN;
            Bs[kk][bn] = B[(size_t)(k0 + kk) * Ncols + bn];
        }
        __syncthreads();
#pragma unroll
        for (int kk = 0; kk < BK; ++kk) {
            float a[TM], b[TN];
#pragma unroll
            for (int i = 0; i < TM; ++i) a[i] = As[kk][trow * TM + i];
#pragma unroll
            for (int j = 0; j < TN; ++j) b[j] = Bs[kk][tcol * TN + j];
#pragma unroll
            for (int i = 0; i < TM; ++i)
#pragma unroll
                for (int j = 0; j < TN; ++j) acc[i][j] += a[i] * b[j];
        }
        __syncthreads();
    }

#pragma unroll
    for (int i = 0; i < TM; ++i) {
        int gr = row0 + trow * TM + i;
        if (gr < M) {
#pragma unroll
            for (int j = 0; j < TN; ++j)
                C[(size_t)gr * Ncols + tcol * TN + j] = acc[i][j];
        }
    }
}

// ---------------------------------------------------------------------------
// Layer-1 edge aggregation: 128 feats/edge, both branches share the hw1 gather.
// ---------------------------------------------------------------------------
__global__ void edge_agg1_kernel(const int* __restrict__ row, const int* __restrict__ col,
                                 const float* __restrict__ ppmi,
                                 const float* __restrict__ dis_g, const float* __restrict__ dis_p,
                                 const float* __restrict__ hw1,
                                 float* __restrict__ acc_g, float* __restrict__ acc_p, int e) {
    int t = blockIdx.x * blockDim.x + threadIdx.x;
    int ei = t >> 7;          // 128 threads per edge
    int f  = t & 127;
    if (ei >= e) return;
    int r = row[ei], c = col[ei];
    float wg = dis_g[r] * dis_g[c];
    float wp = dis_p[r] * ppmi[ei] * dis_p[c];
    float hv = hw1[(size_t)r * HH + f];
    atomicAdd(&acc_g[(size_t)c * HH + f], wg * hv);
    atomicAdd(&acc_p[(size_t)c * HH + f], wp * hv);
}

// finalize layer 1: self-loop term + bias + relu, in place on acc buffers
__global__ void finalize1_kernel(const float* __restrict__ hw1, const float* __restrict__ b1,
                                 const float* __restrict__ dis_g, const float* __restrict__ dis_p,
                                 float* __restrict__ acc_g, float* __restrict__ acc_p, int n) {
    int idx = blockIdx.x * blockDim.x + threadIdx.x;
    if (idx >= n * HH) return;
    int i = idx >> 7;
    int f = idx & 127;
    float dg = dis_g[i], dp = dis_p[i];
    float h  = hw1[idx];
    float bb = b1[f];
    float gv = acc_g[idx] + dg * dg * h + bb;
    float pv = acc_p[idx] + dp * dp * h + bb;
    acc_g[idx] = gv > 0.0f ? gv : 0.0f;
    acc_p[idx] = pv > 0.0f ? pv : 0.0f;
}

// ---------------------------------------------------------------------------
// Layer-2 edge aggregation: 64 feats/edge, branches have separate sources now.
// ---------------------------------------------------------------------------
__global__ void edge_agg2_kernel(const int* __restrict__ row, const int* __restrict__ col,
                                 const float* __restrict__ ppmi,
                                 const float* __restrict__ dis_g, const float* __restrict__ dis_p,
                                 const float* __restrict__ hw2_g, const float* __restrict__ hw2_p,
                                 float* __restrict__ acc2_g, float* __restrict__ acc2_p, int e) {
    int t = blockIdx.x * blockDim.x + threadIdx.x;
    int ei = t >> 6;          // 64 threads per edge
    int f  = t & 63;
    if (ei >= e) return;
    int r = row[ei], c = col[ei];
    float wg = dis_g[r] * dis_g[c];
    float wp = dis_p[r] * ppmi[ei] * dis_p[c];
    atomicAdd(&acc2_g[(size_t)c * OO + f], wg * hw2_g[(size_t)r * OO + f]);
    atomicAdd(&acc2_p[(size_t)c * OO + f], wp * hw2_p[(size_t)r * OO + f]);
}

// ---------------------------------------------------------------------------
// Final: self-loop term + bias, dense gate (dot over 64 feats == one wave),
// softmax over the 2 branches, weighted sum.
// ---------------------------------------------------------------------------
__global__ void final_combine_kernel(const float* __restrict__ acc2_g, const float* __restrict__ acc2_p,
                                     const float* __restrict__ hw2_g, const float* __restrict__ hw2_p,
                                     const float* __restrict__ dis_g, const float* __restrict__ dis_p,
                                     const float* __restrict__ b2,
                                     const float* __restrict__ dense_w, const float* __restrict__ dense_b,
                                     float* __restrict__ out, int n) {
    int t = blockIdx.x * blockDim.x + threadIdx.x;
    int i = t >> 6;           // one wave (64 lanes) per node
    int f = t & 63;
    if (i >= n) return;
    size_t idx = (size_t)i * OO + f;
    float dg = dis_g[i], dp = dis_p[i];
    float gv = acc2_g[idx] + dg * dg * hw2_g[idx] + b2[f];
    float pv = acc2_p[idx] + dp * dp * hw2_p[idx] + b2[f];
    float dw = dense_w[f];
    float sg = gv * dw, sp = pv * dw;
#pragma unroll
    for (int off = 32; off > 0; off >>= 1) {
        sg += __shfl_xor(sg, off, 64);
        sp += __shfl_xor(sp, off, 64);
    }
    float lg = sg + dense_b[0];
    float lp = sp + dense_b[0];
    float m  = fmaxf(lg, lp);
    float eg = expf(lg - m), ep = expf(lp - m);
    float wg = eg / (eg + ep);
    out[idx] = wg * gv + (1.0f - wg) * pv;
}

// ---------------------------------------------------------------------------
extern "C" void kernel_launch(void* const* d_in, const int* in_sizes, int n_in,
                              void* d_out, int out_size, void* d_ws, size_t ws_size,
                              hipStream_t stream) {
    const float* x    = (const float*)d_in[0];
    const int*   ei   = (const int*)d_in[1];
    const float* ppmi = (const float*)d_in[2];
    const float* W1   = (const float*)d_in[3];
    const float* b1   = (const float*)d_in[4];
    const float* W2   = (const float*)d_in[5];
    const float* b2   = (const float*)d_in[6];
    const float* dw   = (const float*)d_in[7];
    const float* db   = (const float*)d_in[8];
    float* out = (float*)d_out;

    const int n = in_sizes[0] / DD;       // 100000
    const int e = in_sizes[2];            // 1600000
    const int* row = ei;
    const int* col = ei + e;

    // workspace layout (floats): dis_g[n], dis_p[n], hw1[n*128] (reused as
    // acc2_g[n*64]+acc2_p[n*64]), acc_g[n*128], acc_p[n*128], hw2_g[n*64], hw2_p[n*64]
    float* ws     = (float*)d_ws;
    float* dis_g  = ws;
    float* dis_p  = dis_g + n;
    float* hw1    = dis_p + n;
    float* acc_g  = hw1   + (size_t)n * HH;
    float* acc_p  = acc_g + (size_t)n * HH;
    float* hw2_g  = acc_p + (size_t)n * HH;
    float* hw2_p  = hw2_g + (size_t)n * OO;
    float* acc2_g = hw1;                    // reuse hw1 region after finalize1
    float* acc2_p = hw1 + (size_t)n * OO;

    const int T = 256;

    // degrees -> dis
    init_deg_kernel<<<(n + T - 1) / T, T, 0, stream>>>(dis_g, dis_p, n);
    accum_deg_kernel<<<(e + T - 1) / T, T, 0, stream>>>(row, ppmi, dis_g, dis_p, e);
    deg_to_dis_kernel<<<(n + T - 1) / T, T, 0, stream>>>(dis_g, dis_p, n);

    // hw1 = x @ W1   (shared by both branches)
    sgemm_kernel<64, 128, 32, 8, 4><<<(n + 63) / 64, 256, 0, stream>>>(x, W1, hw1, n, DD, HH);

    // layer-1 aggregation
    hipMemsetAsync(acc_g, 0, (size_t)n * HH * 2 * sizeof(float), stream);  // acc_g + acc_p contiguous
    {
        long long tot = (long long)e * HH;
        edge_agg1_kernel<<<(unsigned)((tot + T - 1) / T), T, 0, stream>>>(
            row, col, ppmi, dis_g, dis_p, hw1, acc_g, acc_p, e);
    }
    finalize1_kernel<<<((size_t)n * HH + T - 1) / T, T, 0, stream>>>(hw1, b1, dis_g, dis_p, acc_g, acc_p, n);

    // hw2 = g @ W2, p @ W2
    sgemm_kernel<64, 64, 32, 4, 4><<<(n + 63) / 64, 256, 0, stream>>>(acc_g, W2, hw2_g, n, HH, OO);
    sgemm_kernel<64, 64, 32, 4, 4><<<(n + 63) / 64, 256, 0, stream>>>(acc_p, W2, hw2_p, n, HH, OO);

    // layer-2 aggregation (acc2 buffers alias hw1 region — hw1 is dead now)
    hipMemsetAsync(acc2_g, 0, (size_t)n * OO * 2 * sizeof(float), stream);
    {
        long long tot = (long long)e * OO;
        edge_agg2_kernel<<<(unsigned)((tot + T - 1) / T), T, 0, stream>>>(
            row, col, ppmi, dis_g, dis_p, hw2_g, hw2_p, acc2_g, acc2_p, e);
    }

    // finalize + gate
    final_combine_kernel<<<((size_t)n * OO + T - 1) / T, T, 0, stream>>>(
        acc2_g, acc2_p, hw2_g, hw2_p, dis_g, dis_p, b2, dw, db, out, n);
}

// Round 2
// 1339.224 us; speedup vs baseline: 2.0420x; 2.0420x over previous
//
#include <hip/hip_runtime.h>
#include <hip/hip_bf16.h>
#include <math.h>

#define DD 256
#define HH 128
#define OO 64

// ---------------------------------------------------------------------------
// degree kernels
// ---------------------------------------------------------------------------
__global__ void init_deg_kernel(float* __restrict__ deg_g, float* __restrict__ deg_p, int n) {
    int i = blockIdx.x * blockDim.x + threadIdx.x;
    if (i < n) { deg_g[i] = 1.0f; deg_p[i] = 1.0f; }  // self-loop weight
}

__global__ void accum_deg_kernel(const int* __restrict__ row, const float* __restrict__ ppmi,
                                 float* __restrict__ deg_g, float* __restrict__ deg_p, int e) {
    int i = blockIdx.x * blockDim.x + threadIdx.x;
    if (i < e) {
        int r = row[i];
        atomicAdd(&deg_g[r], 1.0f);
        atomicAdd(&deg_p[r], ppmi[i]);
    }
}

__global__ void deg_to_dis_kernel(float* __restrict__ deg_g, float* __restrict__ deg_p, int n) {
    int i = blockIdx.x * blockDim.x + threadIdx.x;
    if (i < n) {
        deg_g[i] = 1.0f / sqrtf(deg_g[i]);
        deg_p[i] = 1.0f / sqrtf(deg_p[i]);
    }
}

// ---------------------------------------------------------------------------
// CSR build: histogram by destination, exclusive scan, cursor fill
// ---------------------------------------------------------------------------
__global__ void hist_col_kernel(const int* __restrict__ col, int* __restrict__ cnt, int e) {
    int i = blockIdx.x * blockDim.x + threadIdx.x;
    if (i < e) atomicAdd(&cnt[col[i]], 1);
}

// scan1: per-block (1024 elems, 256 threads x 4) exclusive scan + block sums
__global__ void scan1_kernel(const int* __restrict__ in, int* __restrict__ out,
                             int* __restrict__ bsums, int n) {
    __shared__ int s[256];
    int tid  = threadIdx.x;
    int base = blockIdx.x * 1024 + tid * 4;
    int v[4]; int tsum = 0;
#pragma unroll
    for (int j = 0; j < 4; ++j) {
        int idx = base + j;
        v[j] = (idx < n) ? in[idx] : 0;
        tsum += v[j];
    }
    s[tid] = tsum;
    __syncthreads();
    for (int off = 1; off < 256; off <<= 1) {
        int t = (tid >= off) ? s[tid - off] : 0;
        __syncthreads();
        s[tid] += t;
        __syncthreads();
    }
    int run = s[tid] - tsum;           // exclusive prefix of this thread's chunk
    if (tid == 255) bsums[blockIdx.x] = s[tid];
#pragma unroll
    for (int j = 0; j < 4; ++j) {
        int idx = base + j;
        if (idx < n) out[idx] = run;
        run += v[j];
    }
}

// scan2: single block scans the (<=256) block sums, in place -> exclusive
__global__ void scan2_kernel(int* __restrict__ bsums, int nb) {
    __shared__ int s[256];
    int tid = threadIdx.x;
    int v = (tid < nb) ? bsums[tid] : 0;
    s[tid] = v;
    __syncthreads();
    for (int off = 1; off < 256; off <<= 1) {
        int t = (tid >= off) ? s[tid - off] : 0;
        __syncthreads();
        s[tid] += t;
        __syncthreads();
    }
    if (tid < nb) bsums[tid] = s[tid] - v;   // exclusive
}

// scan3: add block offsets; also writes row_ptr[n] = e (last thread)
__global__ void scan3_kernel(int* __restrict__ out, const int* __restrict__ bsums, int n, int e) {
    int base = blockIdx.x * 1024 + threadIdx.x * 4;
    int add  = bsums[blockIdx.x];
#pragma unroll
    for (int j = 0; j < 4; ++j) {
        int idx = base + j;
        if (idx < n) out[idx] += add;
    }
    if (blockIdx.x == 0 && threadIdx.x == 0) out[n] = e;
}

// fill: scatter edges into CSR slots; store src id + branch weights (dis[r] parts)
__global__ void fill_csr_kernel(const int* __restrict__ row, const int* __restrict__ col,
                                const float* __restrict__ ppmi,
                                const float* __restrict__ dis_g, const float* __restrict__ dis_p,
                                const int* __restrict__ row_ptr, int* __restrict__ cursor,
                                int* __restrict__ csr_src, float* __restrict__ csr_wg,
                                float* __restrict__ csr_wp, int e) {
    int i = blockIdx.x * blockDim.x + threadIdx.x;
    if (i >= e) return;
    int r = row[i], c = col[i];
    int pos = row_ptr[c] + atomicAdd(&cursor[c], 1);
    csr_src[pos] = r;
    csr_wg[pos]  = dis_g[r];              // gcn edge weight == 1
    csr_wp[pos]  = dis_p[r] * ppmi[i];
}

// ---------------------------------------------------------------------------
// Tiled SGEMM: C[M,Ncols] = A[M,K] @ B[K,Ncols], row-major, BN == Ncols.
// ---------------------------------------------------------------------------
template<int BM, int BN, int BK, int TM, int TN>
__launch_bounds__((BM / TM) * (BN / TN))
__global__ void sgemm_kernel(const float* __restrict__ A, const float* __restrict__ B,
                             float* __restrict__ C, int M, int K, int Ncols) {
    constexpr int THREADS = (BM / TM) * (BN / TN);
    __shared__ float As[BK][BM + 1];
    __shared__ float Bs[BK][BN];

    const int tid  = threadIdx.x;
    const int row0 = blockIdx.x * BM;
    const int tcol = tid % (BN / TN);
    const int trow = tid / (BN / TN);

    float acc[TM][TN];
#pragma unroll
    for (int i = 0; i < TM; ++i)
#pragma unroll
        for (int j = 0; j < TN; ++j) acc[i][j] = 0.0f;

    for (int k0 = 0; k0 < K; k0 += BK) {
        constexpr int A_ITERS = (BM * BK) / THREADS;
#pragma unroll
        for (int l = 0; l < A_ITERS; ++l) {
            int lin = tid + l * THREADS;
            int bm = lin / BK, kk = lin % BK;
            int gr = row0 + bm;
            As[kk][bm] = (gr < M) ? A[(size_t)gr * K + k0 + kk] : 0.0f;
        }
        constexpr int B_ITERS = (BK * BN) / THREADS;
#pragma unroll
        for (int l = 0; l < B_ITERS; ++l) {
            int lin = tid + l * THREADS;
            int kk = lin / BN, bn = lin % BN;
            Bs[kk][bn] = B[(size_t)(k0 + kk) * Ncols + bn];
        }
        __syncthreads();
#pragma unroll
        for (int kk = 0; kk < BK; ++kk) {
            float a[TM], b[TN];
#pragma unroll
            for (int i = 0; i < TM; ++i) a[i] = As[kk][trow * TM + i];
#pragma unroll
            for (int j = 0; j < TN; ++j) b[j] = Bs[kk][tcol * TN + j];
#pragma unroll
            for (int i = 0; i < TM; ++i)
#pragma unroll
                for (int j = 0; j < TN; ++j) acc[i][j] += a[i] * b[j];
        }
        __syncthreads();
    }

#pragma unroll
    for (int i = 0; i < TM; ++i) {
        int gr = row0 + trow * TM + i;
        if (gr < M) {
#pragma unroll
            for (int j = 0; j < TN; ++j)
                C[(size_t)gr * Ncols + tcol * TN + j] = acc[i][j];
        }
    }
}

// ---------------------------------------------------------------------------
// Layer-1 pull aggregation, fused bias+relu. Block=256 -> 2 nodes x 128 feats.
// g = relu(dis_c*(sum wg*hw1[r]) + dis_c^2*hw1[c] + b1), same for p.
// ---------------------------------------------------------------------------
__global__ void agg1_pull_kernel(const int* __restrict__ row_ptr, const int* __restrict__ csr_src,
                                 const float* __restrict__ csr_wg, const float* __restrict__ csr_wp,
                                 const float* __restrict__ hw1,
                                 const float* __restrict__ dis_g, const float* __restrict__ dis_p,
                                 const float* __restrict__ b1,
                                 float* __restrict__ g_out, float* __restrict__ p_out, int n) {
    int c = blockIdx.x * 2 + (threadIdx.x >> 7);
    int f = threadIdx.x & 127;
    if (c >= n) return;
    int beg = row_ptr[c], end = row_ptr[c + 1];
    float sg = 0.0f, sp = 0.0f;
    for (int t = beg; t < end; ++t) {
        int r    = csr_src[t];
        float wg = csr_wg[t];
        float wp = csr_wp[t];
        float hv = hw1[(size_t)r * HH + f];
        sg += wg * hv;
        sp += wp * hv;
    }
    float dgc = dis_g[c], dpc = dis_p[c];
    size_t idx = (size_t)c * HH + f;
    float hself = hw1[idx];
    float bb = b1[f];
    float gv = dgc * sg + dgc * dgc * hself + bb;
    float pv = dpc * sp + dpc * dpc * hself + bb;
    g_out[idx] = gv > 0.0f ? gv : 0.0f;
    p_out[idx] = pv > 0.0f ? pv : 0.0f;
}

// ---------------------------------------------------------------------------
// Layer-2 pull aggregation + self-loop + bias + softmax gate, fused.
// Block=256 -> 4 nodes x 64 feats (one wave per node).
// ---------------------------------------------------------------------------
__global__ void agg2_final_kernel(const int* __restrict__ row_ptr, const int* __restrict__ csr_src,
                                  const float* __restrict__ csr_wg, const float* __restrict__ csr_wp,
                                  const float* __restrict__ hw2_g, const float* __restrict__ hw2_p,
                                  const float* __restrict__ dis_g, const float* __restrict__ dis_p,
                                  const float* __restrict__ b2,
                                  const float* __restrict__ dense_w, const float* __restrict__ dense_b,
                                  float* __restrict__ out, int n) {
    int c = blockIdx.x * 4 + (threadIdx.x >> 6);
    int f = threadIdx.x & 63;
    if (c >= n) return;
    int beg = row_ptr[c], end = row_ptr[c + 1];
    float sg = 0.0f, sp = 0.0f;
    for (int t = beg; t < end; ++t) {
        int r    = csr_src[t];
        float wg = csr_wg[t];
        float wp = csr_wp[t];
        sg += wg * hw2_g[(size_t)r * OO + f];
        sp += wp * hw2_p[(size_t)r * OO + f];
    }
    float dgc = dis_g[c], dpc = dis_p[c];
    size_t idx = (size_t)c * OO + f;
    float bb = b2[f];
    float gv = dgc * sg + dgc * dgc * hw2_g[idx] + bb;
    float pv = dpc * sp + dpc * dpc * hw2_p[idx] + bb;
    // gate: logits = dot(branch, dense_w) + dense_b; softmax over 2 branches
    float dw = dense_w[f];
    float lg = gv * dw, lp = pv * dw;
#pragma unroll
    for (int off = 32; off > 0; off >>= 1) {
        lg += __shfl_xor(lg, off, 64);
        lp += __shfl_xor(lp, off, 64);
    }
    lg += dense_b[0];
    lp += dense_b[0];
    float m  = fmaxf(lg, lp);
    float eg = expf(lg - m), ep = expf(lp - m);
    float wgt = eg / (eg + ep);
    out[idx] = wgt * gv + (1.0f - wgt) * pv;
}

// ---------------------------------------------------------------------------
extern "C" void kernel_launch(void* const* d_in, const int* in_sizes, int n_in,
                              void* d_out, int out_size, void* d_ws, size_t ws_size,
                              hipStream_t stream) {
    const float* x    = (const float*)d_in[0];
    const int*   ei   = (const int*)d_in[1];
    const float* ppmi = (const float*)d_in[2];
    const float* W1   = (const float*)d_in[3];
    const float* b1   = (const float*)d_in[4];
    const float* W2   = (const float*)d_in[5];
    const float* b2   = (const float*)d_in[6];
    const float* dw   = (const float*)d_in[7];
    const float* db   = (const float*)d_in[8];
    float* out = (float*)d_out;

    const int n = in_sizes[0] / DD;       // 100000
    const int e = in_sizes[2];            // 1600000
    const int* row = ei;
    const int* col = ei + e;

    // ---- workspace layout ----
    // floats: dis_g[n] dis_p[n] hw1[128n] g1[128n] p1[128n] csr_wg[E] csr_wp[E]
    // ints  : row_ptr[n+1] cnt[n] csr_src[E] bsums[256]
    // hw2_g/hw2_p alias the hw1 region (hw1 dead after agg1).
    float* ws     = (float*)d_ws;
    float* dis_g  = ws;
    float* dis_p  = dis_g + n;
    float* hw1    = dis_p + n;
    float* g1     = hw1 + (size_t)n * HH;
    float* p1     = g1  + (size_t)n * HH;
    float* csr_wg = p1  + (size_t)n * HH;
    float* csr_wp = csr_wg + e;
    int*   row_ptr = (int*)(csr_wp + e);
    int*   cnt     = row_ptr + (n + 1);
    int*   csr_src = cnt + n;
    int*   bsums   = csr_src + e;
    float* hw2_g  = hw1;                         // reuse
    float* hw2_p  = hw1 + (size_t)n * OO;

    const int T = 256;
    const int nb = (n + 1023) / 1024;            // scan blocks (<=256 supported)

    // degrees -> dis
    init_deg_kernel<<<(n + T - 1) / T, T, 0, stream>>>(dis_g, dis_p, n);
    accum_deg_kernel<<<(e + T - 1) / T, T, 0, stream>>>(row, ppmi, dis_g, dis_p, e);
    deg_to_dis_kernel<<<(n + T - 1) / T, T, 0, stream>>>(dis_g, dis_p, n);

    // CSR build (by destination)
    hipMemsetAsync(cnt, 0, (size_t)n * sizeof(int), stream);
    hist_col_kernel<<<(e + T - 1) / T, T, 0, stream>>>(col, cnt, e);
    scan1_kernel<<<nb, 256, 0, stream>>>(cnt, row_ptr, bsums, n);
    scan2_kernel<<<1, 256, 0, stream>>>(bsums, nb);
    scan3_kernel<<<nb, 256, 0, stream>>>(row_ptr, bsums, n, e);
    hipMemsetAsync(cnt, 0, (size_t)n * sizeof(int), stream);
    fill_csr_kernel<<<(e + T - 1) / T, T, 0, stream>>>(row, col, ppmi, dis_g, dis_p,
                                                       row_ptr, cnt, csr_src, csr_wg, csr_wp, e);

    // hw1 = x @ W1 (shared by both branches)
    sgemm_kernel<64, 128, 32, 8, 4><<<(n + 63) / 64, 256, 0, stream>>>(x, W1, hw1, n, DD, HH);

    // layer-1 pull aggregation (fused bias+relu) -> g1, p1
    agg1_pull_kernel<<<(n + 1) / 2, 256, 0, stream>>>(row_ptr, csr_src, csr_wg, csr_wp,
                                                      hw1, dis_g, dis_p, b1, g1, p1, n);

    // hw2 = g1 @ W2, p1 @ W2 (into reused hw1 region)
    sgemm_kernel<64, 64, 32, 4, 4><<<(n + 63) / 64, 256, 0, stream>>>(g1, W2, hw2_g, n, HH, OO);
    sgemm_kernel<64, 64, 32, 4, 4><<<(n + 63) / 64, 256, 0, stream>>>(p1, W2, hw2_p, n, HH, OO);

    // layer-2 pull aggregation + gate, fused -> out
    agg2_final_kernel<<<(n + 3) / 4, 256, 0, stream>>>(row_ptr, csr_src, csr_wg, csr_wp,
                                                       hw2_g, hw2_p, dis_g, dis_p, b2, dw, db, out, n);
}

// Round 3
// 840.238 us; speedup vs baseline: 3.2546x; 1.5939x over previous
//
#include <hip/hip_runtime.h>
#include <hip/hip_bf16.h>
#include <math.h>

#define DD 256
#define HH 128
#define OO 64

typedef __attribute__((ext_vector_type(8))) __bf16 bf16x8;
typedef __attribute__((ext_vector_type(4))) __bf16 bf16x4;
typedef __attribute__((ext_vector_type(4))) float f32x4;

// ---------------------------------------------------------------------------
// degree kernels
// ---------------------------------------------------------------------------
__global__ void init_deg_kernel(float* __restrict__ deg_g, float* __restrict__ deg_p, int n) {
    int i = blockIdx.x * blockDim.x + threadIdx.x;
    if (i < n) { deg_g[i] = 1.0f; deg_p[i] = 1.0f; }  // self-loop weight
}

__global__ void accum_deg_kernel(const int* __restrict__ row, const float* __restrict__ ppmi,
                                 float* __restrict__ deg_g, float* __restrict__ deg_p, int e) {
    int i = blockIdx.x * blockDim.x + threadIdx.x;
    if (i < e) {
        int r = row[i];
        atomicAdd(&deg_g[r], 1.0f);
        atomicAdd(&deg_p[r], ppmi[i]);
    }
}

__global__ void deg_to_dis_kernel(float* __restrict__ deg_g, float* __restrict__ deg_p, int n) {
    int i = blockIdx.x * blockDim.x + threadIdx.x;
    if (i < n) {
        deg_g[i] = 1.0f / sqrtf(deg_g[i]);
        deg_p[i] = 1.0f / sqrtf(deg_p[i]);
    }
}

// ---------------------------------------------------------------------------
// CSR build
// ---------------------------------------------------------------------------
__global__ void hist_col_kernel(const int* __restrict__ col, int* __restrict__ cnt, int e) {
    int i = blockIdx.x * blockDim.x + threadIdx.x;
    if (i < e) atomicAdd(&cnt[col[i]], 1);
}

__global__ void scan1_kernel(const int* __restrict__ in, int* __restrict__ out,
                             int* __restrict__ bsums, int n) {
    __shared__ int s[256];
    int tid  = threadIdx.x;
    int base = blockIdx.x * 1024 + tid * 4;
    int v[4]; int tsum = 0;
#pragma unroll
    for (int j = 0; j < 4; ++j) {
        int idx = base + j;
        v[j] = (idx < n) ? in[idx] : 0;
        tsum += v[j];
    }
    s[tid] = tsum;
    __syncthreads();
    for (int off = 1; off < 256; off <<= 1) {
        int t = (tid >= off) ? s[tid - off] : 0;
        __syncthreads();
        s[tid] += t;
        __syncthreads();
    }
    int run = s[tid] - tsum;
    if (tid == 255) bsums[blockIdx.x] = s[tid];
#pragma unroll
    for (int j = 0; j < 4; ++j) {
        int idx = base + j;
        if (idx < n) out[idx] = run;
        run += v[j];
    }
}

__global__ void scan2_kernel(int* __restrict__ bsums, int nb) {
    __shared__ int s[256];
    int tid = threadIdx.x;
    int v = (tid < nb) ? bsums[tid] : 0;
    s[tid] = v;
    __syncthreads();
    for (int off = 1; off < 256; off <<= 1) {
        int t = (tid >= off) ? s[tid - off] : 0;
        __syncthreads();
        s[tid] += t;
        __syncthreads();
    }
    if (tid < nb) bsums[tid] = s[tid] - v;
}

__global__ void scan3_kernel(int* __restrict__ out, const int* __restrict__ bsums, int n, int e) {
    int base = blockIdx.x * 1024 + threadIdx.x * 4;
    int add  = bsums[blockIdx.x];
#pragma unroll
    for (int j = 0; j < 4; ++j) {
        int idx = base + j;
        if (idx < n) out[idx] += add;
    }
    if (blockIdx.x == 0 && threadIdx.x == 0) out[n] = e;
}

__global__ void fill_csr_kernel(const int* __restrict__ row, const int* __restrict__ col,
                                const float* __restrict__ ppmi,
                                const float* __restrict__ dis_g, const float* __restrict__ dis_p,
                                const int* __restrict__ row_ptr, int* __restrict__ cursor,
                                int* __restrict__ csr_src, float* __restrict__ csr_wg,
                                float* __restrict__ csr_wp, int e) {
    int i = blockIdx.x * blockDim.x + threadIdx.x;
    if (i >= e) return;
    int r = row[i], c = col[i];
    int pos = row_ptr[c] + atomicAdd(&cursor[c], 1);
    csr_src[pos] = r;
    csr_wg[pos]  = dis_g[r];
    csr_wp[pos]  = dis_p[r] * ppmi[i];
}

// ---------------------------------------------------------------------------
// W -> B^T split-bf16 prep: Bh[n][k] = hi(W[k][n]), Bl = lo residual
// ---------------------------------------------------------------------------
__global__ void conv_w_kernel(const float* __restrict__ W, __bf16* __restrict__ Bh,
                              __bf16* __restrict__ Bl, int K, int N) {
    int i = blockIdx.x * blockDim.x + threadIdx.x;
    if (i >= K * N) return;
    int k = i / N, nn = i % N;
    float v = W[i];
    __bf16 h = (__bf16)v;
    Bh[(size_t)nn * K + k] = h;
    Bl[(size_t)nn * K + k] = (__bf16)(v - (float)h);
}

// ---------------------------------------------------------------------------
// Split-bf16 MFMA GEMM: C[M,BN] = A[M,K] @ B[K,BN], A fp32, B as pre-split B^T.
// BK=32, 256 threads = 4 waves; wave w covers rows [w*BM/4, +BM/4).
// C ~= Ah*Bh + Ah*Bl + Al*Bh  (error ~2^-18, fp32-equivalent for this net)
// ---------------------------------------------------------------------------
template<int BM, int BN>
__launch_bounds__(256, 2)
__global__ void mfma_gemm_kernel(const float* __restrict__ A,
                                 const __bf16* __restrict__ Bth, const __bf16* __restrict__ Btl,
                                 float* __restrict__ C, int M, int K) {
    constexpr int BK  = 32;
    constexpr int LDK = BK + 8;          // 40 bf16 = 80 B row stride (bank spread, 16B-aligned)
    constexpr int WM  = BM / 4;          // rows per wave
    constexpr int MT  = WM / 16;
    constexpr int NT  = BN / 16;
    __shared__ __bf16 Ash[BM * LDK];
    __shared__ __bf16 Asl[BM * LDK];
    __shared__ __bf16 Bsh[BN * LDK];
    __shared__ __bf16 Bsl[BN * LDK];

    const int tid  = threadIdx.x;
    const int wave = tid >> 6;
    const int lane = tid & 63;
    const int quad = lane >> 4;
    const int l16  = lane & 15;
    const int row0 = blockIdx.x * BM;

    f32x4 acc[MT][NT] = {};

    for (int k0 = 0; k0 < K; k0 += BK) {
        // ---- stage A (fp32 -> bf16 hi/lo), BM x 32 ----
#pragma unroll
        for (int p = 0; p < BM / 32; ++p) {
            int lin = p * 256 + tid;         // BM*8 float4 slots
            int r   = lin >> 3;
            int kc  = (lin & 7) * 4;
            int gr  = row0 + r;
            float4 v;
            if (gr < M) v = *(const float4*)(A + (size_t)gr * K + k0 + kc);
            else        v = make_float4(0.f, 0.f, 0.f, 0.f);
            __bf16 h0 = (__bf16)v.x, h1 = (__bf16)v.y, h2 = (__bf16)v.z, h3 = (__bf16)v.w;
            __bf16 l0 = (__bf16)(v.x - (float)h0), l1 = (__bf16)(v.y - (float)h1);
            __bf16 l2 = (__bf16)(v.z - (float)h2), l3 = (__bf16)(v.w - (float)h3);
            *(bf16x4*)&Ash[r * LDK + kc] = (bf16x4){h0, h1, h2, h3};
            *(bf16x4*)&Asl[r * LDK + kc] = (bf16x4){l0, l1, l2, l3};
        }
        // ---- stage B^T (already bf16), BN x 32 ----
#pragma unroll
        for (int p = 0; p < BN / 64; ++p) {
            int lin = p * 256 + tid;         // BN*4 slots of 8 bf16
            int r   = lin >> 2;
            int kc  = (lin & 3) * 8;
            *(uint4*)&Bsh[r * LDK + kc] = *(const uint4*)(Bth + (size_t)r * K + k0 + kc);
            *(uint4*)&Bsl[r * LDK + kc] = *(const uint4*)(Btl + (size_t)r * K + k0 + kc);
        }
        __syncthreads();

        // ---- compute: preload B frags, then MT x NT x 3 mfma ----
        bf16x8 bh[NT], bl[NT];
#pragma unroll
        for (int j = 0; j < NT; ++j) {
            bh[j] = *(const bf16x8*)&Bsh[(j * 16 + l16) * LDK + quad * 8];
            bl[j] = *(const bf16x8*)&Bsl[(j * 16 + l16) * LDK + quad * 8];
        }
#pragma unroll
        for (int i = 0; i < MT; ++i) {
            int m = wave * WM + i * 16 + l16;
            bf16x8 ah = *(const bf16x8*)&Ash[m * LDK + quad * 8];
            bf16x8 al = *(const bf16x8*)&Asl[m * LDK + quad * 8];
#pragma unroll
            for (int j = 0; j < NT; ++j) {
                acc[i][j] = __builtin_amdgcn_mfma_f32_16x16x32_bf16(ah, bh[j], acc[i][j], 0, 0, 0);
                acc[i][j] = __builtin_amdgcn_mfma_f32_16x16x32_bf16(ah, bl[j], acc[i][j], 0, 0, 0);
                acc[i][j] = __builtin_amdgcn_mfma_f32_16x16x32_bf16(al, bh[j], acc[i][j], 0, 0, 0);
            }
        }
        __syncthreads();
    }

    // ---- store: C/D layout col=lane&15, row=quad*4+reg ----
#pragma unroll
    for (int i = 0; i < MT; ++i) {
#pragma unroll
        for (int rg = 0; rg < 4; ++rg) {
            int gr = row0 + wave * WM + i * 16 + quad * 4 + rg;
            if (gr < M) {
#pragma unroll
                for (int j = 0; j < NT; ++j)
                    C[(size_t)gr * BN + j * 16 + l16] = acc[i][j][rg];
            }
        }
    }
}

// ---------------------------------------------------------------------------
// Layer-1 pull aggregation: one wave per node, float2 per lane (128 feats).
// ---------------------------------------------------------------------------
__global__ void agg1_pull_kernel(const int* __restrict__ row_ptr, const int* __restrict__ csr_src,
                                 const float* __restrict__ csr_wg, const float* __restrict__ csr_wp,
                                 const float* __restrict__ hw1,
                                 const float* __restrict__ dis_g, const float* __restrict__ dis_p,
                                 const float* __restrict__ b1,
                                 float* __restrict__ g_out, float* __restrict__ p_out, int n) {
    int c    = blockIdx.x * 4 + (threadIdx.x >> 6);
    int lane = threadIdx.x & 63;
    if (c >= n) return;
    int beg = row_ptr[c], end = row_ptr[c + 1];
    int f2 = lane * 2;
    float sgx = 0.f, sgy = 0.f, spx = 0.f, spy = 0.f;
    int t = beg;
    for (; t + 2 <= end; t += 2) {
        int r0 = csr_src[t], r1 = csr_src[t + 1];
        float wg0 = csr_wg[t], wg1 = csr_wg[t + 1];
        float wp0 = csr_wp[t], wp1 = csr_wp[t + 1];
        float2 h0 = *(const float2*)&hw1[(size_t)r0 * HH + f2];
        float2 h1 = *(const float2*)&hw1[(size_t)r1 * HH + f2];
        sgx += wg0 * h0.x + wg1 * h1.x;
        sgy += wg0 * h0.y + wg1 * h1.y;
        spx += wp0 * h0.x + wp1 * h1.x;
        spy += wp0 * h0.y + wp1 * h1.y;
    }
    if (t < end) {
        int r0 = csr_src[t];
        float wg0 = csr_wg[t], wp0 = csr_wp[t];
        float2 h0 = *(const float2*)&hw1[(size_t)r0 * HH + f2];
        sgx += wg0 * h0.x; sgy += wg0 * h0.y;
        spx += wp0 * h0.x; spy += wp0 * h0.y;
    }
    float dgc = dis_g[c], dpc = dis_p[c];
    size_t idx = (size_t)c * HH + f2;
    float2 hs = *(const float2*)&hw1[idx];
    float bx = b1[f2], by = b1[f2 + 1];
    float gx = dgc * sgx + dgc * dgc * hs.x + bx;
    float gy = dgc * sgy + dgc * dgc * hs.y + by;
    float px = dpc * spx + dpc * dpc * hs.x + bx;
    float py = dpc * spy + dpc * dpc * hs.y + by;
    float2 go, po;
    go.x = gx > 0.f ? gx : 0.f;  go.y = gy > 0.f ? gy : 0.f;
    po.x = px > 0.f ? px : 0.f;  po.y = py > 0.f ? py : 0.f;
    *(float2*)&g_out[idx] = go;
    *(float2*)&p_out[idx] = po;
}

// ---------------------------------------------------------------------------
// Layer-2 pull aggregation + self-loop + bias + softmax gate, fused.
// One wave per node (64 lanes = 64 feats).
// ---------------------------------------------------------------------------
__global__ void agg2_final_kernel(const int* __restrict__ row_ptr, const int* __restrict__ csr_src,
                                  const float* __restrict__ csr_wg, const float* __restrict__ csr_wp,
                                  const float* __restrict__ hw2_g, const float* __restrict__ hw2_p,
                                  const float* __restrict__ dis_g, const float* __restrict__ dis_p,
                                  const float* __restrict__ b2,
                                  const float* __restrict__ dense_w, const float* __restrict__ dense_b,
                                  float* __restrict__ out, int n) {
    int c = blockIdx.x * 4 + (threadIdx.x >> 6);
    int f = threadIdx.x & 63;
    if (c >= n) return;
    int beg = row_ptr[c], end = row_ptr[c + 1];
    float sg = 0.f, sp = 0.f;
    int t = beg;
    for (; t + 2 <= end; t += 2) {
        int r0 = csr_src[t], r1 = csr_src[t + 1];
        float wg0 = csr_wg[t], wg1 = csr_wg[t + 1];
        float wp0 = csr_wp[t], wp1 = csr_wp[t + 1];
        float hg0 = hw2_g[(size_t)r0 * OO + f], hg1 = hw2_g[(size_t)r1 * OO + f];
        float hp0 = hw2_p[(size_t)r0 * OO + f], hp1 = hw2_p[(size_t)r1 * OO + f];
        sg += wg0 * hg0 + wg1 * hg1;
        sp += wp0 * hp0 + wp1 * hp1;
    }
    if (t < end) {
        int r0 = csr_src[t];
        sg += csr_wg[t] * hw2_g[(size_t)r0 * OO + f];
        sp += csr_wp[t] * hw2_p[(size_t)r0 * OO + f];
    }
    float dgc = dis_g[c], dpc = dis_p[c];
    size_t idx = (size_t)c * OO + f;
    float bb = b2[f];
    float gv = dgc * sg + dgc * dgc * hw2_g[idx] + bb;
    float pv = dpc * sp + dpc * dpc * hw2_p[idx] + bb;
    float dw = dense_w[f];
    float lg = gv * dw, lp = pv * dw;
#pragma unroll
    for (int off = 32; off > 0; off >>= 1) {
        lg += __shfl_xor(lg, off, 64);
        lp += __shfl_xor(lp, off, 64);
    }
    lg += dense_b[0];
    lp += dense_b[0];
    float m  = fmaxf(lg, lp);
    float eg = expf(lg - m), ep = expf(lp - m);
    float wgt = eg / (eg + ep);
    out[idx] = wgt * gv + (1.0f - wgt) * pv;
}

// ---------------------------------------------------------------------------
extern "C" void kernel_launch(void* const* d_in, const int* in_sizes, int n_in,
                              void* d_out, int out_size, void* d_ws, size_t ws_size,
                              hipStream_t stream) {
    const float* x    = (const float*)d_in[0];
    const int*   ei   = (const int*)d_in[1];
    const float* ppmi = (const float*)d_in[2];
    const float* W1   = (const float*)d_in[3];
    const float* b1   = (const float*)d_in[4];
    const float* W2   = (const float*)d_in[5];
    const float* b2   = (const float*)d_in[6];
    const float* dw   = (const float*)d_in[7];
    const float* db   = (const float*)d_in[8];
    float* out = (float*)d_out;

    const int n = in_sizes[0] / DD;       // 100000
    const int e = in_sizes[2];            // 1600000
    const int* row = ei;
    const int* col = ei + e;

    // ---- workspace layout ----
    float* ws     = (float*)d_ws;
    float* dis_g  = ws;                              // n
    float* dis_p  = dis_g + n;                       // n
    float* hw1    = dis_p + n;                       // 128n (reused as hw2[2n*64])
    float* g1     = hw1 + (size_t)n * HH;            // 128n
    float* p1     = g1  + (size_t)n * HH;            // 128n (contiguous after g1!)
    float* csr_wg = p1  + (size_t)n * HH;            // e
    float* csr_wp = csr_wg + e;                      // e
    __bf16* bt1h  = (__bf16*)(csr_wp + e);           // 128*256
    __bf16* bt1l  = bt1h + (size_t)DD * HH;
    __bf16* bt2h  = bt1l + (size_t)DD * HH;          // 64*128
    __bf16* bt2l  = bt2h + (size_t)HH * OO;
    int* row_ptr  = (int*)(bt2l + (size_t)HH * OO);  // n+1
    int* cnt      = row_ptr + (n + 1);               // n
    int* csr_src  = cnt + n;                         // e
    int* bsums    = csr_src + e;                     // 256
    float* hw2    = hw1;                             // [2n x 64], g rows then p rows
    float* hw2_g  = hw2;
    float* hw2_p  = hw2 + (size_t)n * OO;

    const int T = 256;
    const int nb = (n + 1023) / 1024;

    // degrees -> dis
    init_deg_kernel<<<(n + T - 1) / T, T, 0, stream>>>(dis_g, dis_p, n);
    accum_deg_kernel<<<(e + T - 1) / T, T, 0, stream>>>(row, ppmi, dis_g, dis_p, e);
    deg_to_dis_kernel<<<(n + T - 1) / T, T, 0, stream>>>(dis_g, dis_p, n);

    // weight prep (B^T, split bf16)
    conv_w_kernel<<<(DD * HH + T - 1) / T, T, 0, stream>>>(W1, bt1h, bt1l, DD, HH);
    conv_w_kernel<<<(HH * OO + T - 1) / T, T, 0, stream>>>(W2, bt2h, bt2l, HH, OO);

    // CSR build (by destination)
    hipMemsetAsync(cnt, 0, (size_t)n * sizeof(int), stream);
    hist_col_kernel<<<(e + T - 1) / T, T, 0, stream>>>(col, cnt, e);
    scan1_kernel<<<nb, 256, 0, stream>>>(cnt, row_ptr, bsums, n);
    scan2_kernel<<<1, 256, 0, stream>>>(bsums, nb);
    scan3_kernel<<<nb, 256, 0, stream>>>(row_ptr, bsums, n, e);
    hipMemsetAsync(cnt, 0, (size_t)n * sizeof(int), stream);
    fill_csr_kernel<<<(e + T - 1) / T, T, 0, stream>>>(row, col, ppmi, dis_g, dis_p,
                                                       row_ptr, cnt, csr_src, csr_wg, csr_wp, e);

    // hw1 = x @ W1 (split-bf16 MFMA)
    mfma_gemm_kernel<128, HH><<<(n + 127) / 128, 256, 0, stream>>>(x, bt1h, bt1l, hw1, n, DD);

    // layer-1 pull aggregation (fused bias+relu) -> g1, p1
    agg1_pull_kernel<<<(n + 3) / 4, 256, 0, stream>>>(row_ptr, csr_src, csr_wg, csr_wp,
                                                      hw1, dis_g, dis_p, b1, g1, p1, n);

    // hw2 = [g1; p1] @ W2  — single batched MFMA GEMM over 2n rows
    mfma_gemm_kernel<128, OO><<<(2 * n + 127) / 128, 256, 0, stream>>>(g1, bt2h, bt2l, hw2, 2 * n, HH);

    // layer-2 pull aggregation + gate, fused -> out
    agg2_final_kernel<<<(n + 3) / 4, 256, 0, stream>>>(row_ptr, csr_src, csr_wg, csr_wp,
                                                       hw2_g, hw2_p, dis_g, dis_p, b2, dw, db, out, n);
}